// Round 4
// baseline (185.652 us; speedup 1.0000x reference)
//
#include <hip/hip_runtime.h>
#include <hip/hip_bf16.h>

#define Bq 128
#define Tq 4096
#define Nq 32
#define SEGL 128
#define NSEG 32
#define BURN 16
#define TRIPB 15         // BURN-1
#define UNR 4
#define NBLK 36          // UNR*NBLK = 144 >= 143 max steps
#define LOG2E 1.4426950408889634f

typedef float v2f __attribute__((ext_vector_type(2)));
typedef unsigned short u16;

__device__ __forceinline__ unsigned pack_bf16(float f0, float f1) {  // RNE pack
  unsigned u0 = __float_as_uint(f0);
  unsigned u1 = __float_as_uint(f1);
  u0 = u0 + 0x7fffu + ((u0 >> 16) & 1u);
  u1 = u1 + 0x7fffu + ((u1 >> 16) & 1u);
  return (u0 >> 16) | (u1 & 0xffff0000u);
}

// 4 chains per wave, 16 lanes/chain, 2 output columns/lane.
// State vector lives in LDS as 32 bf16 per chain; each lane reads all 16 dwords
// (4 x b128, 2-way bank alias = free) and computes its 2 columns with pk_fma.
// Same segmented-scan + burn-in + skip/window logic as the verified r3 kernel.
extern "C" __global__ void __launch_bounds__(256)
crf_chain_kernel(const float* __restrict__ pot, const int* __restrict__ lengths,
                 const float* __restrict__ trans,
                 u16* __restrict__ eaF, u16* __restrict__ eaB,
                 float* __restrict__ iacc) {
  __shared__ unsigned xbuf[16][16];   // 16 chains x 16 dwords (32 bf16)
  const int tid = threadIdx.x;
  if (blockIdx.x == 0 && tid < Bq) iacc[tid] = 0.f;  // zero dice accumulators

  const int cslot = tid >> 4;          // chain slot in block (0..15)
  const int sub = tid & 15;
  const int oc = sub * 2;              // output columns oc, oc+1
  const int cid = blockIdx.x * 16 + cslot;
  const int b = cid >> 6;
  const int dir = (cid >> 5) & 1;      // 0 fwd, 1 bwd
  const int s = cid & 31;
  const int len = lengths[b];
  const int sL = s * SEGL;
  const bool active = (sL < len);
  if (__ballot(active) == 0ull) return;

  const int lenm1 = len - 1;
  const int tend = min(sL + SEGL, len);
  const int end = tend - 1;
  const int t1 = min(lenm1, end + BURN);
  const int dstep = dir ? -1 : 1;
  const int cst = dir ? (end + BURN) : ((s == 0) ? (1 - TRIPB) : (sL - BURN + 1));
  const int skip = dir ? (end + BURN - t1) : ((s == 0) ? TRIPB : 0);
  const int wlo = sL;
  const int whi = dir ? min(end, t1) : end;
  const unsigned uspan = (unsigned)(whi - wlo);

  // eT: fwd col j sums trans[i][j]; bwd "col" i sums trans[i][j] over j.
  v2f eTa[16], eTb[16];
#pragma unroll
  for (int k = 0; k < 16; ++k) {
    const int i0 = 2 * k, i1 = 2 * k + 1;
    float a0 = dir ? trans[oc * Nq + i0] : trans[i0 * Nq + oc];
    float a1 = dir ? trans[oc * Nq + i1] : trans[i1 * Nq + oc];
    float b0 = dir ? trans[(oc + 1) * Nq + i0] : trans[i0 * Nq + oc + 1];
    float b1 = dir ? trans[(oc + 1) * Nq + i1] : trans[i1 * Nq + oc + 1];
    v2f ea, eb;
    ea.x = exp2f(a0 * LOG2E); ea.y = exp2f(a1 * LOG2E);
    eb.x = exp2f(b0 * LOG2E); eb.y = exp2f(b1 * LOG2E);
    eTa[k] = ea; eTb[k] = eb;
  }

  const float* pb = pot + (size_t)b * Tq * Nq;
  float raw0, raw1;
  if (dir) { raw0 = 1.f; raw1 = 1.f; }
  else {
    const int rinit = (s == 0) ? 0 : (sL - BURN);
    raw0 = exp2f(pb[rinit * Nq + oc] * LOG2E);
    raw1 = exp2f(pb[rinit * Nq + oc + 1] * LOG2E);
  }
  u16* outbase = (dir ? eaB : eaF) + ((size_t)b * Tq) * Nq + oc;
  if (!dir) { if (active && s == 0) *(unsigned*)outbase = pack_bf16(raw0, raw1); }
  else      { if (active && t1 <= end) *(unsigned*)(outbase + (size_t)t1 * Nq) = pack_bf16(1.f, 1.f); }

  int cb = cst;                          // block-base cursor
  int r = cst - dir;                     // row written this step
  u16* outp = outbase + (ptrdiff_t)r * Nq;
  v2f pn[UNR];
#pragma unroll
  for (int k = 0; k < UNR; ++k) {
    int cc = min(max(cb + dstep * k, 0), lenm1);
    pn[k] = *(const v2f*)(pb + cc * Nq + oc);
  }

  int g0 = 0;
#pragma unroll 1
  for (int blk = 0; blk < NBLK; ++blk) {
    v2f pc[UNR];
#pragma unroll
    for (int k = 0; k < UNR; ++k) pc[k] = pn[k];
#pragma unroll
    for (int k = 0; k < UNR; ++k) {
      int cc = min(max(cb + dstep * (k + UNR), 0), lenm1);
      pn[k] = *(const v2f*)(pb + cc * Nq + oc);
    }
#pragma unroll
    for (int k = 0; k < UNR; ++k) {
      float ep0 = exp2f(pc[k].x * LOG2E);
      float ep1 = exp2f(pc[k].y * LOG2E);
      float w0 = dir ? raw0 * ep0 : raw0;
      float w1 = dir ? raw1 * ep1 : raw1;
      xbuf[cslot][sub] = pack_bf16(w0, w1);
      const uint4* xb4 = (const uint4*)&xbuf[cslot][0];
      uint4 B0 = xb4[0], B1 = xb4[1], B2 = xb4[2], B3 = xb4[3];
      int eb = (int)((B0.x << 16) & 0x7f800000u);
      float corr = __int_as_float(0x7f000000 - eb);
      v2f a0, a1, a2, a3, d0, d1, d2, d3;
      a0 = 0.f; a1 = 0.f; a2 = 0.f; a3 = 0.f;
      d0 = 0.f; d1 = 0.f; d2 = 0.f; d3 = 0.f;
#define ACC(dw, p, A, D) { v2f xp; \
      xp.x = __uint_as_float((dw) << 16); \
      xp.y = __uint_as_float((dw) & 0xffff0000u); \
      A += xp * eTa[p]; D += xp * eTb[p]; }
      ACC(B0.x, 0, a0, d0) ACC(B0.y, 1, a1, d1) ACC(B0.z, 2, a2, d2) ACC(B0.w, 3, a3, d3)
      ACC(B1.x, 4, a0, d0) ACC(B1.y, 5, a1, d1) ACC(B1.z, 6, a2, d2) ACC(B1.w, 7, a3, d3)
      ACC(B2.x, 8, a0, d0) ACC(B2.y, 9, a1, d1) ACC(B2.z,10, a2, d2) ACC(B2.w,11, a3, d3)
      ACC(B3.x,12, a0, d0) ACC(B3.y,13, a1, d1) ACC(B3.z,14, a2, d2) ACC(B3.w,15, a3, d3)
#undef ACC
      v2f sa = (a0 + a1) + (a2 + a3);
      v2f sd = (d0 + d1) + (d2 + d3);
      float s0 = sa.x + sa.y;
      float s1 = sd.x + sd.y;
      float n0 = s0 * corr * (dir ? 1.f : ep0);
      float n1 = s1 * corr * (dir ? 1.f : ep1);
      const bool upd = (g0 + k) >= skip;
      raw0 = upd ? n0 : raw0;
      raw1 = upd ? n1 : raw1;
      if (active && (unsigned)(r - wlo) <= uspan) *(unsigned*)outp = pack_bf16(raw0, raw1);
      outp += dstep * Nq;
      r += dstep;
    }
    cb += dstep * UNR;
    g0 += UNR;
  }
}

// One THREAD per position; 2048 blocks. p_t[y]/sum via per-row normalization.
extern "C" __global__ void __launch_bounds__(256)
dice_kernel(const u16* __restrict__ eaF, const u16* __restrict__ eaB,
            const int* __restrict__ y, const int* __restrict__ lengths,
            float* __restrict__ iacc) {
  const int b = blockIdx.x >> 4;
  const int q = blockIdx.x & 15;
  const int len = lengths[b];
  if (q * 256 >= len) return;
  const int t = q * 256 + threadIdx.x;
  float I = 0.f;
  if (t < len) {
    const size_t base = ((size_t)b * Tq + t) * Nq;
    const uint4* a4 = (const uint4*)(eaF + base);
    const uint4* b4 = (const uint4*)(eaB + base);
    float c0 = 0.f, c1 = 0.f, c2 = 0.f, c3 = 0.f;
#pragma unroll
    for (int w = 0; w < 4; ++w) {
      uint4 ua = a4[w], ub = b4[w];
      c0 = fmaf(__uint_as_float(ua.x << 16), __uint_as_float(ub.x << 16), c0);
      c1 = fmaf(__uint_as_float(ua.x & 0xffff0000u), __uint_as_float(ub.x & 0xffff0000u), c1);
      c2 = fmaf(__uint_as_float(ua.y << 16), __uint_as_float(ub.y << 16), c2);
      c3 = fmaf(__uint_as_float(ua.y & 0xffff0000u), __uint_as_float(ub.y & 0xffff0000u), c3);
      c0 = fmaf(__uint_as_float(ua.z << 16), __uint_as_float(ub.z << 16), c0);
      c1 = fmaf(__uint_as_float(ua.z & 0xffff0000u), __uint_as_float(ub.z & 0xffff0000u), c1);
      c2 = fmaf(__uint_as_float(ua.w << 16), __uint_as_float(ub.w << 16), c2);
      c3 = fmaf(__uint_as_float(ua.w & 0xffff0000u), __uint_as_float(ub.w & 0xffff0000u), c3);
    }
    float v = (c0 + c1) + (c2 + c3);
    int yt = y[(size_t)b * Tq + t];
    float ay = __uint_as_float(((unsigned)eaF[base + yt]) << 16);
    float by = __uint_as_float(((unsigned)eaB[base + yt]) << 16);
    I = (ay * by) / v;
  }
#pragma unroll
  for (int m = 1; m < 64; m <<= 1) I += __shfl_xor(I, m);
  __shared__ float sI[4];
  if ((threadIdx.x & 63) == 0) sI[threadIdx.x >> 6] = I;
  __syncthreads();
  if (threadIdx.x == 0) atomicAdd(&iacc[b], sI[0] + sI[1] + sI[2] + sI[3]);
}

extern "C" __global__ void final_kernel(const float* __restrict__ iacc,
                                        const int* __restrict__ lengths,
                                        float* __restrict__ out) {
  const int b = threadIdx.x;
  if (b < Bq) out[b] = 1.f - (2.f * iacc[b] + 1.f) / (2.f * (float)lengths[b] + 1.f);
}

extern "C" void kernel_launch(void* const* d_in, const int* in_sizes, int n_in,
                              void* d_out, int out_size, void* d_ws, size_t ws_size,
                              hipStream_t stream) {
  const float* pot = (const float*)d_in[0];
  const int* y_true = (const int*)d_in[1];
  const int* lengths = (const int*)d_in[2];
  const float* trans = (const float*)d_in[3];
  float* out = (float*)d_out;

  char* ws = (char*)d_ws;
  const size_t n_elems = (size_t)Bq * Tq * Nq;       // 16,777,216
  u16* eaF = (u16*)ws;                               // 32 MiB
  u16* eaB = (u16*)(ws + n_elems * 2);               // 32 MiB
  float* iacc = (float*)(ws + n_elems * 4);          // 512 B

  crf_chain_kernel<<<512, 256, 0, stream>>>(pot, lengths, trans, eaF, eaB, iacc);
  dice_kernel<<<Bq * 16, 256, 0, stream>>>(eaF, eaB, y_true, lengths, iacc);
  final_kernel<<<1, 128, 0, stream>>>(iacc, lengths, out);
}